// Round 10
// baseline (782.542 us; speedup 1.0000x reference)
//
#include <hip/hip_runtime.h>
#include <hip/hip_cooperative_groups.h>
#include <math.h>

#define B    4
#define T    16384
#define A    256
#define K    256
#define PAD  128
#define TP   (T + 2*PAD)      // 16640
#define TOUT (TP - K + 1)     // 16385
#define ITERS 16
#define CHUNK 512
#define NCHUNK 33
#define NCP  36               // padded per-atom chunk stride
#define TILE 2048
#define NTILE 9
#define NBLK 512              // grid: 128 blocks per batch, block owns atoms (2a0, 2a0+1)
#define BTH  512              // threads per block (8 waves)
#define NBB  128              // blocks per batch

struct Smem {
    float rp[2336];           // 580 quads staged window/tile
    float dnAB[2*K];          // own two atoms, contiguous
    float dnsel[K];           // picked atom
    float wv[16]; int wi[16];
    float fv; int fi;
};

#define TAP(acc, s0,s1,s2,s3, dq) { acc = fmaf(s0,(dq).x,acc); acc = fmaf(s1,(dq).y,acc); \
                                    acc = fmaf(s2,(dq).z,acc); acc = fmaf(s3,(dq).w,acc); }

__device__ __forceinline__ void wave_amax(float& bv, int& bi) {
    #pragma unroll
    for (int off = 32; off; off >>= 1) {
        float ov = __shfl_down(bv, off);
        int   oi = __shfl_down(bi, off);
        if (ov > bv || (ov == bv && oi < bi)) { bv = ov; bi = oi; }
    }
}

// Per-batch grid barrier (fan-in 128). Safe only under cooperative launch.
__device__ __forceinline__ void gbar(unsigned* c, unsigned target) {
    __syncthreads();
    if (threadIdx.x == 0) {
        __hip_atomic_fetch_add(c, 1u, __ATOMIC_RELEASE, __HIP_MEMORY_SCOPE_AGENT);
        while (__hip_atomic_load(c, __ATOMIC_ACQUIRE, __HIP_MEMORY_SCOPE_AGENT) < target)
            __builtin_amdgcn_s_sleep(2);
    }
    __syncthreads();
}

// ---------- norm (each batch writes dn redundantly - identical values) + init ----------
__device__ __forceinline__ void dev_norm_init(int a0, int b, int tid,
                                              const float* __restrict__ x,
                                              const float* __restrict__ d,
                                              float* __restrict__ dn,
                                              float* __restrict__ rp,
                                              float* __restrict__ recon, Smem& sm) {
    int lane = tid & 63, w = tid >> 6;
    int half = tid >> 8, k = tid & 255;
    int atom = a0*2 + half;
    float v = d[atom*K + k];
    float sq = v*v;
    #pragma unroll
    for (int off = 32; off; off >>= 1) sq += __shfl_down(sq, off);
    if (lane == 0) sm.wv[w] = sq;
    __syncthreads();
    float norm = sqrtf(sm.wv[half*4] + sm.wv[half*4+1] + sm.wv[half*4+2] + sm.wv[half*4+3]) + 1e-12f;
    dn[atom*K + k] = v / norm;
    __syncthreads();
    for (int i = a0*BTH + tid; i < TP; i += NBB*BTH) {
        float xv = (i >= PAD && i < PAD + T) ? x[b*T + (i - PAD)] : 0.f;
        rp[(size_t)b*TP + i] = xv;
        recon[(size_t)b*TP + i] = 0.f;
    }
}

// ---------- full conv for 2 atoms, TM=4 per thread, chunk maxima -> segval ----------
__device__ void dev_conv(int a0, int b, int tid, const float* __restrict__ rp,
                         const float* __restrict__ dn,
                         float* __restrict__ segval, int* __restrict__ segidx,
                         float* __restrict__ abv, int* __restrict__ abi, Smem& sm) {
    const int aA = a0*2, aB = aA + 1;
    const int lane = tid & 63, w = tid >> 6;
    sm.dnAB[tid] = dn[aA*K + tid];                 // 512 floats = both atoms
    const float4* rp4 = (const float4*)(rp + (size_t)b*TP);

    for (int tile = 0; tile < NTILE; tile++) {
        int t0 = tile * TILE;
        __syncthreads();
        float4* s4 = (float4*)sm.rp;
        for (int i = tid; i < 580; i += BTH) {
            int g = t0/4 + i;
            float4 v = {0.f,0.f,0.f,0.f};
            if (g*4 < TP) v = rp4[g];
            s4[i] = v;
        }
        __syncthreads();
        const float4* srp4 = (const float4*)sm.rp;
        const float4* dA4  = (const float4*)sm.dnAB;
        const float4* dB4  = dA4 + 64;
        float accA[4] = {0,0,0,0}, accB[4] = {0,0,0,0};
        float4 p = srp4[tid];
        #pragma unroll 4
        for (int kq = 0; kq < 64; kq++) {
            float4 dA = dA4[kq];
            float4 dB = dB4[kq];
            float4 pn = srp4[tid + kq + 1];
            TAP(accA[0], p.x,p.y,p.z,p.w, dA); TAP(accA[1], p.y,p.z,p.w,pn.x, dA);
            TAP(accA[2], p.z,p.w,pn.x,pn.y, dA); TAP(accA[3], p.w,pn.x,pn.y,pn.z, dA);
            TAP(accB[0], p.x,p.y,p.z,p.w, dB); TAP(accB[1], p.y,p.z,p.w,pn.x, dB);
            TAP(accB[2], p.z,p.w,pn.x,pn.y, dB); TAP(accB[3], p.w,pn.x,pn.y,pn.z, dB);
            p = pn;
        }
        int lt = tid * 4;
        float bvA = -INFINITY, bvB = -INFINITY;
        int biA = 0x7fffffff, biB = 0x7fffffff;
        #pragma unroll
        for (int j = 0; j < 4; j++) {
            int t = t0 + lt + j;
            if (t < TOUT) {
                if (accA[j] > bvA) { bvA = accA[j]; biA = aA*TOUT + t; }
                if (accB[j] > bvB) { bvB = accB[j]; biB = aB*TOUT + t; }
            }
        }
        wave_amax(bvA, biA); wave_amax(bvB, biB);
        if (lane == 0) { sm.wv[w] = bvA; sm.wi[w] = biA; sm.wv[8+w] = bvB; sm.wi[8+w] = biB; }
        __syncthreads();
        // chunk c in tile (0..3): waves 2c, 2c+1
        if (tid < 4) {
            float v0 = sm.wv[2*tid];   int i0 = sm.wi[2*tid];
            float v1 = sm.wv[2*tid+1]; int i1 = sm.wi[2*tid+1];
            if (v1 > v0 || (v1 == v0 && i1 < i0)) { v0 = v1; i0 = i1; }
            int chunk = tile*4 + tid;
            if (chunk < NCHUNK) {
                segval[((size_t)b*A + aA)*NCP + chunk] = v0;
                segidx[((size_t)b*A + aA)*NCP + chunk] = i0;
            }
        } else if (tid >= 64 && tid < 68) {
            int c = tid - 64;
            float v0 = sm.wv[8+2*c];   int i0 = sm.wi[8+2*c];
            float v1 = sm.wv[8+2*c+1]; int i1 = sm.wi[8+2*c+1];
            if (v1 > v0 || (v1 == v0 && i1 < i0)) { v0 = v1; i0 = i1; }
            int chunk = tile*4 + c;
            if (chunk < NCHUNK) {
                segval[((size_t)b*A + aB)*NCP + chunk] = v0;
                segidx[((size_t)b*A + aB)*NCP + chunk] = i0;
            }
        }
    }
    __syncthreads();
    if (w < 2) {     // wave0 -> atom A, wave1 -> atom B
        int atom = (w == 0) ? aA : aB;
        float bv = -INFINITY; int bi = 0x7fffffff;
        if (lane < NCHUNK) {
            bv = segval[((size_t)b*A + atom)*NCP + lane];
            bi = segidx[((size_t)b*A + atom)*NCP + lane];
        }
        wave_amax(bv, bi);
        if (lane == 0) { abv[b*A + atom] = bv; abi[b*A + atom] = bi; }
    }
}

// ---------- one matching-pursuit iteration ----------
__device__ void dev_iter(int a0, int b, int tid, int last,
                         const float* __restrict__ avc, const int* __restrict__ aic,
                         float* __restrict__ avn, int* __restrict__ ain,
                         const float* __restrict__ rin, float* __restrict__ rout,
                         float* __restrict__ recon, const float* __restrict__ dn,
                         float* __restrict__ segval, int* __restrict__ segidx, Smem& sm) {
    const int aA = a0*2, aB = aA + 1;
    const int lane = tid & 63, w = tid >> 6;
    // pick (redundant, deterministic across blocks of same b)
    {
        float bv = avc[b*A + (tid & 255)];
        int   bi = aic[b*A + (tid & 255)];
        wave_amax(bv, bi);
        if (lane == 0) { sm.wv[w] = bv; sm.wi[w] = bi; }
        __syncthreads();
        if (tid == 0) {
            bv = sm.wv[0]; bi = sm.wi[0];
            for (int j = 1; j < 8; j++)
                if (sm.wv[j] > bv || (sm.wv[j] == bv && sm.wi[j] < bi)) { bv = sm.wv[j]; bi = sm.wi[j]; }
            sm.fv = bv; sm.fi = bi;
        }
        __syncthreads();
    }
    float val = sm.fv; int idx = sm.fi;
    int atom = idx / TOUT, pos = idx - atom*TOUT;
    if (tid < K) sm.dnsel[tid] = dn[atom*K + tid];
    sm.dnAB[tid] = dn[aA*K + tid];

    int lo = pos - (K-1); if (lo < 0) lo = 0;
    int c_base = (lo >> 9) & ~1;          // 2-chunk-aligned; dirty chunks within [c_base, c_base+4)
    int tbase = c_base * CHUNK;

    if (!last) {   // stage 4-chunk window [tbase, tbase+2320)
        const float4* rin4 = (const float4*)(rin + (size_t)b*TP);
        float4* s4 = (float4*)sm.rp;
        for (int i = tid; i < 580; i += BTH) {
            int g = tbase/4 + i;
            float4 v = {0.f,0.f,0.f,0.f};
            if (g*4 < TP) v = rin4[g];
            s4[i] = v;
        }
    }
    __syncthreads();
    if (!last) {   // distributed rp copy+update: 4160 quads over blocks a0=0..8
        const float4* rin4 = (const float4*)(rin + (size_t)b*TP);
        float4* rout4 = (float4*)(rout + (size_t)b*TP);
        int i = a0*BTH + tid;
        if (i < TP/4) {
            float4 v = rin4[i];
            int o = i*4 - pos;
            if (o > -4 && o < K) {
                if (o+0 >= 0 && o+0 < K) v.x -= val * sm.dnsel[o+0];
                if (o+1 >= 0 && o+1 < K) v.y -= val * sm.dnsel[o+1];
                if (o+2 >= 0 && o+2 < K) v.z -= val * sm.dnsel[o+2];
                if (o+3 >= 0 && o+3 < K) v.w -= val * sm.dnsel[o+3];
            }
            rout4[i] = v;
        }
    }
    if (a0 == 0 && tid < K) recon[(size_t)b*TP + pos + tid] += val * sm.dnsel[tid];
    if (last) return;

    // apply update delta in LDS (changed region [pos, pos+K) is inside the window)
    if (tid < K) sm.rp[pos - tbase + tid] -= val * sm.dnsel[tid];
    __syncthreads();

    // recompute 2048 outputs [tbase, tbase+2048) for both atoms (conv-identical chain)
    const float4* srp4 = (const float4*)sm.rp;
    const float4* dA4  = (const float4*)sm.dnAB;
    const float4* dB4  = dA4 + 64;
    float accA[4] = {0,0,0,0}, accB[4] = {0,0,0,0};
    float4 p = srp4[tid];
    #pragma unroll 4
    for (int kq = 0; kq < 64; kq++) {
        float4 dA = dA4[kq];
        float4 dB = dB4[kq];
        float4 pn = srp4[tid + kq + 1];
        TAP(accA[0], p.x,p.y,p.z,p.w, dA); TAP(accA[1], p.y,p.z,p.w,pn.x, dA);
        TAP(accA[2], p.z,p.w,pn.x,pn.y, dA); TAP(accA[3], p.w,pn.x,pn.y,pn.z, dA);
        TAP(accB[0], p.x,p.y,p.z,p.w, dB); TAP(accB[1], p.y,p.z,p.w,pn.x, dB);
        TAP(accB[2], p.z,p.w,pn.x,pn.y, dB); TAP(accB[3], p.w,pn.x,pn.y,pn.z, dB);
        p = pn;
    }
    int lt = tid * 4;
    float bvA = -INFINITY, bvB = -INFINITY;
    int biA = 0x7fffffff, biB = 0x7fffffff;
    #pragma unroll
    for (int j = 0; j < 4; j++) {
        int t = tbase + lt + j;
        if (t < TOUT) {
            if (accA[j] > bvA) { bvA = accA[j]; biA = aA*TOUT + t; }
            if (accB[j] > bvB) { bvB = accB[j]; biB = aB*TOUT + t; }
        }
    }
    wave_amax(bvA, biA); wave_amax(bvB, biB);
    if (lane == 0) { sm.wv[w] = bvA; sm.wi[w] = biA; sm.wv[8+w] = bvB; sm.wi[8+w] = biB; }
    __syncthreads();
    if (tid < 4) {
        float v0 = sm.wv[2*tid];   int i0 = sm.wi[2*tid];
        float v1 = sm.wv[2*tid+1]; int i1 = sm.wi[2*tid+1];
        if (v1 > v0 || (v1 == v0 && i1 < i0)) { v0 = v1; i0 = i1; }
        int chunk = c_base + tid;
        if (chunk < NCHUNK) {
            segval[((size_t)b*A + aA)*NCP + chunk] = v0;
            segidx[((size_t)b*A + aA)*NCP + chunk] = i0;
        }
    } else if (tid >= 64 && tid < 68) {
        int c = tid - 64;
        float v0 = sm.wv[8+2*c];   int i0 = sm.wi[8+2*c];
        float v1 = sm.wv[8+2*c+1]; int i1 = sm.wi[8+2*c+1];
        if (v1 > v0 || (v1 == v0 && i1 < i0)) { v0 = v1; i0 = i1; }
        int chunk = c_base + c;
        if (chunk < NCHUNK) {
            segval[((size_t)b*A + aB)*NCP + chunk] = v0;
            segidx[((size_t)b*A + aB)*NCP + chunk] = i0;
        }
    }
    __syncthreads();
    if (w < 2) {   // refresh per-atom best over all chunks
        int at = (w == 0) ? aA : aB;
        float bv = -INFINITY; int bi = 0x7fffffff;
        if (lane < NCHUNK) {
            bv = segval[((size_t)b*A + at)*NCP + lane];
            bi = segidx[((size_t)b*A + at)*NCP + lane];
        }
        wave_amax(bv, bi);
        if (lane == 0) { avn[b*A + at] = bv; ain[b*A + at] = bi; }
    }
}

// ================= cooperative single-kernel path =================
// launch_bounds(512,2): empirical allocator law (R5/R6/R9): cap ~ 256/arg2.
// arg2=4 put k_coop in a ~60-VGPR bucket and spilled ~17 MB/iter (R9, 270 MB
// WRITE_SIZE). arg2=2 -> cap 128, fits the ~90 live regs; occupancy stays
// grid-limited at 2 blocks/CU (16 waves, ~50%) regardless.
__global__ void __launch_bounds__(BTH, 2)
k_coop(const float* __restrict__ x, const float* __restrict__ d, float* __restrict__ out,
       float* __restrict__ dn, float* __restrict__ rp0, float* __restrict__ rp1,
       float* __restrict__ recon, float* __restrict__ segval, int* __restrict__ segidx,
       float* __restrict__ abv0, int* __restrict__ abi0,
       float* __restrict__ abv1, int* __restrict__ abi1, unsigned* __restrict__ bar) {
    __shared__ Smem sm;
    const int bid = blockIdx.x, tid = threadIdx.x;
    const int a0 = bid & (NBB-1), b = bid >> 7;
    unsigned* bar_b = bar + b*256;          // per-batch counter, 1 KB apart
    unsigned gen = 0;
    dev_norm_init(a0, b, tid, x, d, dn, rp0, recon, sm);
    gen++; gbar(bar_b, gen*NBB);
    dev_conv(a0, b, tid, rp0, dn, segval, segidx, abv0, abi0, sm);
    gen++; gbar(bar_b, gen*NBB);
    const float* rin = rp0; float* rout = rp1;
    const float* avc = abv0; const int* aic = abi0;
    float* avn = abv1; int* ain = abi1;
    for (int it = 0; it < ITERS; it++) {
        dev_iter(a0, b, tid, it == ITERS-1, avc, aic, avn, ain,
                 rin, rout, recon, dn, segval, segidx, sm);
        { const float* t1 = rin; rin = rout; rout = (float*)t1; }
        { const float* t2 = avc; avc = avn; avn = (float*)t2; }
        { const int*   t3 = aic; aic = ain; ain = (int*)t3; }
        gen++; gbar(bar_b, gen*NBB);
    }
    for (int i = a0*BTH + tid; i < T; i += NBB*BTH)
        out[b*T + i] = recon[(size_t)b*TP + PAD + i];
}

// ================= non-cooperative fallback path =================
__global__ void __launch_bounds__(BTH) k_f_norm_init(const float* x, const float* d,
                                                     float* dn, float* rp0, float* recon) {
    __shared__ Smem sm;
    dev_norm_init(blockIdx.x & (NBB-1), blockIdx.x >> 7, threadIdx.x, x, d, dn, rp0, recon, sm);
}
__global__ void __launch_bounds__(BTH, 2) k_f_conv(const float* rp, const float* dn,
                                                   float* segval, int* segidx,
                                                   float* abv, int* abi) {
    __shared__ Smem sm;
    dev_conv(blockIdx.x & (NBB-1), blockIdx.x >> 7, threadIdx.x, rp, dn, segval, segidx, abv, abi, sm);
}
__global__ void __launch_bounds__(BTH, 2) k_f_iter(int last,
                                                   const float* avc, const int* aic,
                                                   float* avn, int* ain,
                                                   const float* rin, float* rout,
                                                   float* recon, const float* dn,
                                                   float* segval, int* segidx) {
    __shared__ Smem sm;
    dev_iter(blockIdx.x & (NBB-1), blockIdx.x >> 7, threadIdx.x, last,
             avc, aic, avn, ain, rin, rout, recon, dn, segval, segidx, sm);
}
__global__ void k_f_out(const float* recon, float* out) {
    int i = blockIdx.x * blockDim.x + threadIdx.x;
    if (i >= B*T) return;
    int b = i / T, t = i - b*T;
    out[i] = recon[(size_t)b*TP + PAD + t];
}

extern "C" void kernel_launch(void* const* d_in, const int* in_sizes, int n_in,
                              void* d_out, int out_size, void* d_ws, size_t ws_size,
                              hipStream_t stream) {
    const float* x = (const float*)d_in[0];
    const float* d = (const float*)d_in[1];
    float* out = (float*)d_out;

    float* ws     = (float*)d_ws;
    float* dn     = ws;                                   // A*K
    float* rp0    = dn  + (size_t)A*K;                    // B*TP
    float* rp1    = rp0 + (size_t)B*TP;                   // B*TP
    float* recon  = rp1 + (size_t)B*TP;                   // B*TP
    float* segval = recon + (size_t)B*TP;                 // B*A*NCP
    int*   segidx = (int*)(segval + (size_t)B*A*NCP);     // B*A*NCP
    float* abv0   = (float*)(segidx + (size_t)B*A*NCP);   // B*A
    float* abv1   = abv0 + (size_t)B*A;                   // B*A
    int*   abi0   = (int*)(abv1 + (size_t)B*A);           // B*A
    int*   abi1   = abi0 + (size_t)B*A;                   // B*A
    unsigned* bar = (unsigned*)(abi1 + (size_t)B*A);      // 4 per-batch counters, 1 KB apart

    // deterministic cooperative-launch feasibility check (host queries only)
    int nb = 0, ncu = 0;
    hipError_t e1 = hipOccupancyMaxActiveBlocksPerMultiprocessor(&nb, (const void*)k_coop, BTH, 0);
    hipError_t e2 = hipDeviceGetAttribute(&ncu, hipDeviceAttributeMultiprocessorCount, 0);
    bool coop = (e1 == hipSuccess && e2 == hipSuccess && nb > 0 && ncu > 0 &&
                 (long)nb * ncu >= NBLK);
    if (coop) {
        hipMemsetAsync(bar, 0, 4*256*sizeof(unsigned), stream);   // zero counters (graph-safe)
        void* args[] = {(void*)&x, (void*)&d, (void*)&out, (void*)&dn,
                        (void*)&rp0, (void*)&rp1, (void*)&recon,
                        (void*)&segval, (void*)&segidx,
                        (void*)&abv0, (void*)&abi0, (void*)&abv1, (void*)&abi1,
                        (void*)&bar};
        hipError_t e = hipLaunchCooperativeKernel((const void*)k_coop, dim3(NBLK), dim3(BTH),
                                                  args, 0, stream);
        if (e == hipSuccess) return;
    }
    // fallback: same device code, separate launches, double-buffered (race-free)
    k_f_norm_init<<<NBLK, BTH, 0, stream>>>(x, d, dn, rp0, recon);
    k_f_conv<<<NBLK, BTH, 0, stream>>>(rp0, dn, segval, segidx, abv0, abi0);
    float* rbuf[2] = {rp0, rp1};
    float* av[2]   = {abv0, abv1};
    int*   ai[2]   = {abi0, abi1};
    for (int it = 0; it < ITERS; it++) {
        k_f_iter<<<NBLK, BTH, 0, stream>>>(it == ITERS-1 ? 1 : 0,
                                           av[it & 1], ai[it & 1],
                                           av[(it + 1) & 1], ai[(it + 1) & 1],
                                           rbuf[it & 1], rbuf[(it + 1) & 1],
                                           recon, dn, segval, segidx);
    }
    k_f_out<<<(B*T + 255)/256, 256, 0, stream>>>(recon, out);
}

// Round 11
// 738.746 us; speedup vs baseline: 1.0593x; 1.0593x over previous
//
#include <hip/hip_runtime.h>
#include <math.h>

#define B    4
#define T    16384
#define A    256
#define K    256
#define PAD  128
#define TP   (T + 2*PAD)      // 16640
#define TOUT (TP - K + 1)     // 16385
#define ITERS 16
#define CHUNK 512
#define NCHUNK 33
#define NCP  36
#define TILE 2048
#define NTILE 9

template<int NA> struct SmemT {
    float rp[2336];           // 580 quads staged tile/window
    float dnAB[NA*K];         // own atoms
    float dnsel[K];           // picked atom
    float wv[16]; int wi[16];
    float fv; int fi;
};

#define TAP(acc, s0,s1,s2,s3, dq) { acc = fmaf(s0,(dq).x,acc); acc = fmaf(s1,(dq).y,acc); \
                                    acc = fmaf(s2,(dq).z,acc); acc = fmaf(s3,(dq).w,acc); }

__device__ __forceinline__ void wave_amax(float& bv, int& bi) {
    #pragma unroll
    for (int off = 32; off; off >>= 1) {
        float ov = __shfl_down(bv, off);
        int   oi = __shfl_down(bi, off);
        if (ov > bv || (ov == bv && oi < bi)) { bv = ov; bi = oi; }
    }
}

// Per-batch grid barrier. Safe only under cooperative launch.
__device__ __forceinline__ void gbar(unsigned* c, unsigned target) {
    __syncthreads();
    if (threadIdx.x == 0) {
        __hip_atomic_fetch_add(c, 1u, __ATOMIC_RELEASE, __HIP_MEMORY_SCOPE_AGENT);
        while (__hip_atomic_load(c, __ATOMIC_ACQUIRE, __HIP_MEMORY_SCOPE_AGENT) < target)
            __builtin_amdgcn_s_sleep(2);
    }
    __syncthreads();
}

template<int NA>
__device__ __forceinline__ void dev_norm_init(int a0, int b, int tid,
        const float* __restrict__ x, const float* __restrict__ d,
        float* __restrict__ dn, float* __restrict__ rp, float* __restrict__ recon,
        SmemT<NA>& sm) {
    const int lane = tid & 63, w = tid >> 6;
    constexpr int NBB = A / NA;
    #pragma unroll
    for (int s = 0; s < NA; s++) {
        int atom = a0*NA + s;
        float v = d[atom*K + tid];
        float sq = v*v;
        #pragma unroll
        for (int off = 32; off; off >>= 1) sq += __shfl_down(sq, off);
        if (lane == 0) sm.wv[w] = sq;
        __syncthreads();
        float norm = sqrtf(sm.wv[0] + sm.wv[1] + sm.wv[2] + sm.wv[3]) + 1e-12f;
        dn[atom*K + tid] = v / norm;
        __syncthreads();
    }
    for (int i = a0*256 + tid; i < TP; i += NBB*256) {
        float xv = (i >= PAD && i < PAD + T) ? x[b*T + (i - PAD)] : 0.f;
        rp[(size_t)b*TP + i] = xv;
        recon[(size_t)b*TP + i] = 0.f;
    }
}

template<int NA>
__device__ __forceinline__ void dev_conv(int a0, int b, int tid,
        const float* __restrict__ rp, const float* __restrict__ dn,
        float* __restrict__ segval, int* __restrict__ segidx,
        float* __restrict__ abv, int* __restrict__ abi, SmemT<NA>& sm) {
    const int lane = tid & 63, w = tid >> 6;
    for (int i = tid; i < NA*K; i += 256) sm.dnAB[i] = dn[(a0*NA)*K + i];
    const float4* rp4 = (const float4*)(rp + (size_t)b*TP);

    for (int tile = 0; tile < NTILE; tile++) {
        const int t0 = tile * TILE;
        __syncthreads();
        float4* s4 = (float4*)sm.rp;
        for (int i = tid; i < 580; i += 256) {
            int g = t0/4 + i;
            float4 v = {0.f,0.f,0.f,0.f};
            if (g*4 < TP) v = rp4[g];
            s4[i] = v;
        }
        __syncthreads();
        const float4* srp4 = (const float4*)sm.rp;
        const float4* dq4  = (const float4*)sm.dnAB;
        float acc[NA][2][4];
        #pragma unroll
        for (int s = 0; s < NA; s++)
            #pragma unroll
            for (int g = 0; g < 2; g++)
                #pragma unroll
                for (int j = 0; j < 4; j++) acc[s][g][j] = 0.f;
        float4 p = srp4[tid];
        float4 q = srp4[tid + 256];
        #pragma unroll 4
        for (int kq = 0; kq < 64; kq++) {
            float4 pn = srp4[tid + kq + 1];
            float4 qn = srp4[tid + 256 + kq + 1];
            #pragma unroll
            for (int s = 0; s < NA; s++) {
                float4 dq = dq4[s*64 + kq];
                TAP(acc[s][0][0], p.x,p.y,p.z,p.w, dq);
                TAP(acc[s][0][1], p.y,p.z,p.w,pn.x, dq);
                TAP(acc[s][0][2], p.z,p.w,pn.x,pn.y, dq);
                TAP(acc[s][0][3], p.w,pn.x,pn.y,pn.z, dq);
                TAP(acc[s][1][0], q.x,q.y,q.z,q.w, dq);
                TAP(acc[s][1][1], q.y,q.z,q.w,qn.x, dq);
                TAP(acc[s][1][2], q.z,q.w,qn.x,qn.y, dq);
                TAP(acc[s][1][3], q.w,qn.x,qn.y,qn.z, dq);
            }
            p = pn; q = qn;
        }
        const int lt = tid * 4;
        #pragma unroll
        for (int s = 0; s < NA; s++) {
            #pragma unroll
            for (int g = 0; g < 2; g++) {
                float bv = -INFINITY; int bi = 0x7fffffff;
                #pragma unroll
                for (int j = 0; j < 4; j++) {
                    int t = t0 + g*1024 + lt + j;
                    if (t < TOUT && acc[s][g][j] > bv) { bv = acc[s][g][j]; bi = (a0*NA+s)*TOUT + t; }
                }
                wave_amax(bv, bi);
                if (lane == 0) { sm.wv[s*8 + g*4 + w] = bv; sm.wi[s*8 + g*4 + w] = bi; }
            }
        }
        __syncthreads();
        if (w < NA && lane < 4) {   // wave s writes atom s's 4 chunks of this tile
            int s = w;
            float v0 = sm.wv[s*8 + 2*lane];   int i0 = sm.wi[s*8 + 2*lane];
            float v1 = sm.wv[s*8 + 2*lane+1]; int i1 = sm.wi[s*8 + 2*lane+1];
            if (v1 > v0 || (v1 == v0 && i1 < i0)) { v0 = v1; i0 = i1; }
            int chunk = tile*4 + lane;
            if (chunk < NCHUNK) {
                int atom = a0*NA + s;
                segval[((size_t)b*A + atom)*NCP + chunk] = v0;
                segidx[((size_t)b*A + atom)*NCP + chunk] = i0;
            }
        }
    }
    __syncthreads();
    if (w < NA) {
        int atom = a0*NA + w;
        float bv = -INFINITY; int bi = 0x7fffffff;
        if (lane < NCHUNK) {
            bv = segval[((size_t)b*A + atom)*NCP + lane];
            bi = segidx[((size_t)b*A + atom)*NCP + lane];
        }
        wave_amax(bv, bi);
        if (lane == 0) { abv[b*A + atom] = bv; abi[b*A + atom] = bi; }
    }
}

template<int NA>
__device__ __forceinline__ void dev_iter(int a0, int b, int tid, int last,
        const float* __restrict__ avc, const int* __restrict__ aic,
        float* __restrict__ avn, int* __restrict__ ain,
        const float* __restrict__ rin, float* __restrict__ rout,
        float* __restrict__ recon, const float* __restrict__ dn,
        float* __restrict__ segval, int* __restrict__ segidx, SmemT<NA>& sm) {
    const int lane = tid & 63, w = tid >> 6;
    // pick (redundant, deterministic across blocks of same b)
    {
        float bv = avc[b*A + tid]; int bi = aic[b*A + tid];
        wave_amax(bv, bi);
        if (lane == 0) { sm.wv[w] = bv; sm.wi[w] = bi; }
        __syncthreads();
        if (tid == 0) {
            bv = sm.wv[0]; bi = sm.wi[0];
            for (int j = 1; j < 4; j++)
                if (sm.wv[j] > bv || (sm.wv[j] == bv && sm.wi[j] < bi)) { bv = sm.wv[j]; bi = sm.wi[j]; }
            sm.fv = bv; sm.fi = bi;
        }
        __syncthreads();
    }
    float val = sm.fv; int idx = sm.fi;
    int atom = idx / TOUT, pos = idx - atom*TOUT;
    sm.dnsel[tid] = dn[atom*K + tid];
    for (int i = tid; i < NA*K; i += 256) sm.dnAB[i] = dn[(a0*NA)*K + i];

    int lo = pos - (K-1); if (lo < 0) lo = 0;
    int c_lo = lo >> 9;
    int tbase = c_lo * CHUNK;

    if (!last) {   // stage 2-chunk window + K halo
        const float4* rin4 = (const float4*)(rin + (size_t)b*TP);
        float4* s4 = (float4*)sm.rp;
        for (int i = tid; i < 324; i += 256) {
            int g = tbase/4 + i;
            float4 v = {0.f,0.f,0.f,0.f};
            if (g*4 < TP) v = rin4[g];
            s4[i] = v;
        }
    }
    __syncthreads();
    if (!last) {   // distributed rp copy+update across first 17 blocks per batch
        const float4* rin4 = (const float4*)(rin + (size_t)b*TP);
        float4* rout4 = (float4*)(rout + (size_t)b*TP);
        int i = a0*256 + tid;
        if (i < TP/4) {
            float4 v = rin4[i];
            int o = i*4 - pos;
            if (o > -4 && o < K) {
                if (o+0 >= 0 && o+0 < K) v.x -= val * sm.dnsel[o+0];
                if (o+1 >= 0 && o+1 < K) v.y -= val * sm.dnsel[o+1];
                if (o+2 >= 0 && o+2 < K) v.z -= val * sm.dnsel[o+2];
                if (o+3 >= 0 && o+3 < K) v.w -= val * sm.dnsel[o+3];
            }
            rout4[i] = v;
        }
    }
    if (a0 == 0) recon[(size_t)b*TP + pos + tid] += val * sm.dnsel[tid];
    if (last) return;

    sm.rp[pos - tbase + tid] -= val * sm.dnsel[tid];
    __syncthreads();

    // recompute 1024 outputs [tbase, tbase+1024), conv-identical fma chain
    const float4* srp4 = (const float4*)sm.rp;
    const float4* dq4  = (const float4*)sm.dnAB;
    float acc[NA][4];
    #pragma unroll
    for (int s = 0; s < NA; s++)
        #pragma unroll
        for (int j = 0; j < 4; j++) acc[s][j] = 0.f;
    float4 p = srp4[tid];
    #pragma unroll 4
    for (int kq = 0; kq < 64; kq++) {
        float4 pn = srp4[tid + kq + 1];
        #pragma unroll
        for (int s = 0; s < NA; s++) {
            float4 dq = dq4[s*64 + kq];
            TAP(acc[s][0], p.x,p.y,p.z,p.w, dq);
            TAP(acc[s][1], p.y,p.z,p.w,pn.x, dq);
            TAP(acc[s][2], p.z,p.w,pn.x,pn.y, dq);
            TAP(acc[s][3], p.w,pn.x,pn.y,pn.z, dq);
        }
        p = pn;
    }
    const int lt = tid * 4;
    #pragma unroll
    for (int s = 0; s < NA; s++) {
        float bv = -INFINITY; int bi = 0x7fffffff;
        #pragma unroll
        for (int j = 0; j < 4; j++) {
            int t = tbase + lt + j;
            if (t < TOUT && acc[s][j] > bv) { bv = acc[s][j]; bi = (a0*NA+s)*TOUT + t; }
        }
        wave_amax(bv, bi);
        if (lane == 0) { sm.wv[s*8 + w] = bv; sm.wi[s*8 + w] = bi; }
    }
    __syncthreads();
    if (w < NA && lane < 2) {   // wave s writes atom s's 2 dirty chunks
        int s = w;
        float v0 = sm.wv[s*8 + 2*lane];   int i0 = sm.wi[s*8 + 2*lane];
        float v1 = sm.wv[s*8 + 2*lane+1]; int i1 = sm.wi[s*8 + 2*lane+1];
        if (v1 > v0 || (v1 == v0 && i1 < i0)) { v0 = v1; i0 = i1; }
        int chunk = c_lo + lane;
        if (chunk < NCHUNK) {
            int at = a0*NA + s;
            segval[((size_t)b*A + at)*NCP + chunk] = v0;
            segidx[((size_t)b*A + at)*NCP + chunk] = i0;
        }
    }
    __syncthreads();
    if (w < NA) {   // refresh per-atom best
        int at = a0*NA + w;
        float bv = -INFINITY; int bi = 0x7fffffff;
        if (lane < NCHUNK) {
            bv = segval[((size_t)b*A + at)*NCP + lane];
            bi = segidx[((size_t)b*A + at)*NCP + lane];
        }
        wave_amax(bv, bi);
        if (lane == 0) { avn[b*A + at] = bv; ain[b*A + at] = bi; }
    }
}

template<int NA>
__device__ __forceinline__ void coop_body(
        const float* x, const float* d, float* out, float* dn,
        float* rp0, float* rp1, float* recon, float* segval, int* segidx,
        float* abv0, int* abi0, float* abv1, int* abi1, unsigned* bar) {
    __shared__ SmemT<NA> sm;
    constexpr int NBB = A / NA;
    const int bid = blockIdx.x, tid = threadIdx.x;
    const int a0 = bid & (NBB - 1), b = bid / NBB;
    unsigned* bar_b = bar + b*256;
    unsigned gen = 0;
    dev_norm_init<NA>(a0, b, tid, x, d, dn, rp0, recon, sm);
    gen++; gbar(bar_b, gen*NBB);
    dev_conv<NA>(a0, b, tid, rp0, dn, segval, segidx, abv0, abi0, sm);
    gen++; gbar(bar_b, gen*NBB);
    const float* rin = rp0; float* rout = rp1;
    const float* avc = abv0; const int* aic = abi0;
    float* avn = abv1; int* ain = abi1;
    for (int it = 0; it < ITERS; it++) {
        dev_iter<NA>(a0, b, tid, it == ITERS-1, avc, aic, avn, ain,
                     rin, rout, recon, dn, segval, segidx, sm);
        { const float* t1 = rin; rin = rout; rout = (float*)t1; }
        { const float* t2 = avc; avc = avn; avn = (float*)t2; }
        { const int*   t3 = aic; aic = ain; ain = (int*)t3; }
        gen++; gbar(bar_b, gen*NBB);
    }
    for (int i = a0*256 + tid; i < T; i += NBB*256)
        out[b*T + i] = recon[(size_t)b*TP + PAD + i];
}

// launch_bounds(256,2): allocator law (R5/R6/R9): VGPR cap ~256/arg2; arg2=2
// -> 128 cap, no spill (R6: 116 VGPR clean). Residency is grid/thread-limited,
// not bound-limited.
__global__ void __launch_bounds__(256, 2)
k_coop1(const float* x, const float* d, float* out, float* dn,
        float* rp0, float* rp1, float* recon, float* segval, int* segidx,
        float* abv0, int* abi0, float* abv1, int* abi1, unsigned* bar) {
    coop_body<1>(x, d, out, dn, rp0, rp1, recon, segval, segidx, abv0, abi0, abv1, abi1, bar);
}
__global__ void __launch_bounds__(256, 2)
k_coop2(const float* x, const float* d, float* out, float* dn,
        float* rp0, float* rp1, float* recon, float* segval, int* segidx,
        float* abv0, int* abi0, float* abv1, int* abi1, unsigned* bar) {
    coop_body<2>(x, d, out, dn, rp0, rp1, recon, segval, segidx, abv0, abi0, abv1, abi1, bar);
}

// ================= non-cooperative fallback (NA=2, 512 blocks) =================
__global__ void __launch_bounds__(256) k_f_norm_init(const float* x, const float* d,
                                                     float* dn, float* rp0, float* recon) {
    __shared__ SmemT<2> sm;
    dev_norm_init<2>(blockIdx.x & 127, blockIdx.x >> 7, threadIdx.x, x, d, dn, rp0, recon, sm);
}
__global__ void __launch_bounds__(256, 2) k_f_conv(const float* rp, const float* dn,
                                                   float* segval, int* segidx,
                                                   float* abv, int* abi) {
    __shared__ SmemT<2> sm;
    dev_conv<2>(blockIdx.x & 127, blockIdx.x >> 7, threadIdx.x, rp, dn, segval, segidx, abv, abi, sm);
}
__global__ void __launch_bounds__(256, 2) k_f_iter(int last,
                                                   const float* avc, const int* aic,
                                                   float* avn, int* ain,
                                                   const float* rin, float* rout,
                                                   float* recon, const float* dn,
                                                   float* segval, int* segidx) {
    __shared__ SmemT<2> sm;
    dev_iter<2>(blockIdx.x & 127, blockIdx.x >> 7, threadIdx.x, last,
                avc, aic, avn, ain, rin, rout, recon, dn, segval, segidx, sm);
}
__global__ void k_f_out(const float* recon, float* out) {
    int i = blockIdx.x * blockDim.x + threadIdx.x;
    if (i >= B*T) return;
    int b = i / T, t = i - b*T;
    out[i] = recon[(size_t)b*TP + PAD + t];
}

extern "C" void kernel_launch(void* const* d_in, const int* in_sizes, int n_in,
                              void* d_out, int out_size, void* d_ws, size_t ws_size,
                              hipStream_t stream) {
    const float* x = (const float*)d_in[0];
    const float* d = (const float*)d_in[1];
    float* out = (float*)d_out;

    float* ws     = (float*)d_ws;
    float* dn     = ws;                                   // A*K
    float* rp0    = dn  + (size_t)A*K;                    // B*TP
    float* rp1    = rp0 + (size_t)B*TP;                   // B*TP
    float* recon  = rp1 + (size_t)B*TP;                   // B*TP
    float* segval = recon + (size_t)B*TP;                 // B*A*NCP
    int*   segidx = (int*)(segval + (size_t)B*A*NCP);     // B*A*NCP
    float* abv0   = (float*)(segidx + (size_t)B*A*NCP);   // B*A
    float* abv1   = abv0 + (size_t)B*A;                   // B*A
    int*   abi0   = (int*)(abv1 + (size_t)B*A);           // B*A
    int*   abi1   = abi0 + (size_t)B*A;                   // B*A
    unsigned* bar = (unsigned*)(abi1 + (size_t)B*A);      // 4 per-batch counters, 1 KB apart

    int ncu = 0;
    hipDeviceGetAttribute(&ncu, hipDeviceAttributeMultiprocessorCount, 0);
    void* args[] = {(void*)&x, (void*)&d, (void*)&out, (void*)&dn,
                    (void*)&rp0, (void*)&rp1, (void*)&recon,
                    (void*)&segval, (void*)&segidx,
                    (void*)&abv0, (void*)&abi0, (void*)&abv1, (void*)&abi1,
                    (void*)&bar};

    // tier 1: NA=1, 1024 blocks (4/CU) — highest occupancy
    int nb1 = 0;
    if (hipOccupancyMaxActiveBlocksPerMultiprocessor(&nb1, (const void*)k_coop1, 256, 0)
            == hipSuccess && ncu > 0 && (long)nb1 * ncu >= 1024) {
        hipMemsetAsync(bar, 0, 4*256*sizeof(unsigned), stream);
        if (hipLaunchCooperativeKernel((const void*)k_coop1, dim3(1024), dim3(256),
                                       args, 0, stream) == hipSuccess)
            return;
    }
    // tier 2: NA=2, 512 blocks (2/CU) — R8-proven config
    int nb2 = 0;
    if (hipOccupancyMaxActiveBlocksPerMultiprocessor(&nb2, (const void*)k_coop2, 256, 0)
            == hipSuccess && ncu > 0 && (long)nb2 * ncu >= 512) {
        hipMemsetAsync(bar, 0, 4*256*sizeof(unsigned), stream);
        if (hipLaunchCooperativeKernel((const void*)k_coop2, dim3(512), dim3(256),
                                       args, 0, stream) == hipSuccess)
            return;
    }
    // tier 3: non-cooperative, 19 launches, race-free via double buffers
    k_f_norm_init<<<512, 256, 0, stream>>>(x, d, dn, rp0, recon);
    k_f_conv<<<512, 256, 0, stream>>>(rp0, dn, segval, segidx, abv0, abi0);
    float* rbuf[2] = {rp0, rp1};
    float* av[2]   = {abv0, abv1};
    int*   ai[2]   = {abi0, abi1};
    for (int it = 0; it < ITERS; it++) {
        k_f_iter<<<512, 256, 0, stream>>>(it == ITERS-1 ? 1 : 0,
                                          av[it & 1], ai[it & 1],
                                          av[(it + 1) & 1], ai[(it + 1) & 1],
                                          rbuf[it & 1], rbuf[(it + 1) & 1],
                                          recon, dn, segval, segidx);
    }
    k_f_out<<<(B*T + 255)/256, 256, 0, stream>>>(recon, out);
}

// Round 12
// 721.488 us; speedup vs baseline: 1.0846x; 1.0239x over previous
//
#include <hip/hip_runtime.h>
#include <math.h>

#define B    4
#define T    16384
#define A    256
#define K    256
#define PAD  128
#define TP   (T + 2*PAD)      // 16640
#define TOUT (TP - K + 1)     // 16385
#define ITERS 16
#define CHUNK 512
#define NCHUNK 33
#define NCP  36
#define TILE 2048
#define NTILE 9
#define NBB  128              // iter blocks per batch (atom pairs)
#define NITB (NBB*B)          // 512 iteration blocks

#define TAP(acc, s0,s1,s2,s3, dq) { acc = fmaf(s0,(dq).x,acc); acc = fmaf(s1,(dq).y,acc); \
                                    acc = fmaf(s2,(dq).z,acc); acc = fmaf(s3,(dq).w,acc); }

struct __align__(16) SmemIt {
    float rp[1304];           // 324 staged quads (1296) + pad
    float dn[2*K];            // own two atoms
    float sel[K];             // picked atom
    float wv[16]; int wi[16];
    float fv; int fi;
};

__device__ __forceinline__ void wave_amax(float& bv, int& bi) {
    #pragma unroll
    for (int off = 32; off; off >>= 1) {
        float ov = __shfl_down(bv, off);
        int   oi = __shfl_down(bi, off);
        if (ov > bv || (ov == bv && oi < bi)) { bv = ov; bi = oi; }
    }
}

// Per-batch grid barrier (fan-in 128). Safe only under cooperative launch.
__device__ __forceinline__ void gbar(unsigned* c, unsigned target) {
    __syncthreads();
    if (threadIdx.x == 0) {
        __hip_atomic_fetch_add(c, 1u, __ATOMIC_RELEASE, __HIP_MEMORY_SCOPE_AGENT);
        while (__hip_atomic_load(c, __ATOMIC_ACQUIRE, __HIP_MEMORY_SCOPE_AGENT) < target)
            __builtin_amdgcn_s_sleep(2);
    }
    __syncthreads();
}

// ---------------- norm + init (ordinary launch, grid A) ----------------
__global__ __launch_bounds__(256) void k_norm_init(const float* __restrict__ x,
        const float* __restrict__ d, float* __restrict__ dn,
        float* __restrict__ rp, float* __restrict__ recon) {
    __shared__ float ls[4];
    int a = blockIdx.x, tid = threadIdx.x;
    int lane = tid & 63, w = tid >> 6;
    float v = d[a*K + tid];
    float sq = v*v;
    #pragma unroll
    for (int off = 32; off; off >>= 1) sq += __shfl_down(sq, off);
    if (lane == 0) ls[w] = sq;
    __syncthreads();
    float norm = sqrtf(ls[0] + ls[1] + ls[2] + ls[3]) + 1e-12f;
    dn[a*K + tid] = v / norm;
    for (int i = blockIdx.x*256 + tid; i < B*TP; i += A*256) {
        int bb = i / TP, t = i - bb*TP;
        float xv = (t >= PAD && t < PAD + T) ? x[bb*T + (t - PAD)] : 0.f;
        rp[i] = xv;
        recon[i] = 0.f;
    }
}

// ---------------- full conv (ordinary launch, grid (9,128,4)) ----------------
// Block = (tile, atom-pair, batch). 2 atoms share the staged tile: 4 b128 LDS
// reads per 64 FMAs per k-step. launch_bounds(256,2): allocator law
// (R5/R6/R9/R11): VGPR cap ~256/arg2; arg2=4 spills (R5: 311MB scratch).
__global__ __launch_bounds__(256, 2) void k_conv(const float* __restrict__ rp,
        const float* __restrict__ dn,
        float* __restrict__ segval, int* __restrict__ segidx) {
    __shared__ float s_rp[2336];
    __shared__ float s_dn[2*K];
    __shared__ float wv[16]; __shared__ int wi[16];
    const int tid = threadIdx.x, lane = tid & 63, w = tid >> 6;
    const int a0 = blockIdx.y, b = blockIdx.z;
    const int aA = a0*2;
    const int t0 = blockIdx.x * TILE;
    s_dn[tid] = dn[aA*K + tid];
    s_dn[256 + tid] = dn[aA*K + 256 + tid];
    const float4* rp4 = (const float4*)(rp + (size_t)b*TP);
    float4* s4 = (float4*)s_rp;
    for (int i = tid; i < 580; i += 256) {
        int g = t0/4 + i;
        float4 v = {0.f,0.f,0.f,0.f};
        if (g*4 < TP) v = rp4[g];
        s4[i] = v;
    }
    __syncthreads();
    const float4* srp4 = (const float4*)s_rp;
    const float4* dA4 = (const float4*)s_dn;
    const float4* dB4 = dA4 + 64;
    float acc[2][2][4];
    #pragma unroll
    for (int s = 0; s < 2; s++)
        #pragma unroll
        for (int g = 0; g < 2; g++)
            #pragma unroll
            for (int j = 0; j < 4; j++) acc[s][g][j] = 0.f;
    float4 p = srp4[tid], q = srp4[tid + 256];
    #pragma unroll 4
    for (int kq = 0; kq < 64; kq++) {
        float4 pn = srp4[tid + kq + 1];
        float4 qn = srp4[tid + 256 + kq + 1];
        float4 dA = dA4[kq], dB = dB4[kq];
        TAP(acc[0][0][0], p.x,p.y,p.z,p.w, dA); TAP(acc[0][0][1], p.y,p.z,p.w,pn.x, dA);
        TAP(acc[0][0][2], p.z,p.w,pn.x,pn.y, dA); TAP(acc[0][0][3], p.w,pn.x,pn.y,pn.z, dA);
        TAP(acc[0][1][0], q.x,q.y,q.z,q.w, dA); TAP(acc[0][1][1], q.y,q.z,q.w,qn.x, dA);
        TAP(acc[0][1][2], q.z,q.w,qn.x,qn.y, dA); TAP(acc[0][1][3], q.w,qn.x,qn.y,qn.z, dA);
        TAP(acc[1][0][0], p.x,p.y,p.z,p.w, dB); TAP(acc[1][0][1], p.y,p.z,p.w,pn.x, dB);
        TAP(acc[1][0][2], p.z,p.w,pn.x,pn.y, dB); TAP(acc[1][0][3], p.w,pn.x,pn.y,pn.z, dB);
        TAP(acc[1][1][0], q.x,q.y,q.z,q.w, dB); TAP(acc[1][1][1], q.y,q.z,q.w,qn.x, dB);
        TAP(acc[1][1][2], q.z,q.w,qn.x,qn.y, dB); TAP(acc[1][1][3], q.w,qn.x,qn.y,qn.z, dB);
        p = pn; q = qn;
    }
    const int lt = tid * 4;
    #pragma unroll
    for (int s = 0; s < 2; s++) {
        #pragma unroll
        for (int g = 0; g < 2; g++) {
            float bv = -INFINITY; int bi = 0x7fffffff;
            #pragma unroll
            for (int j = 0; j < 4; j++) {
                int t = t0 + g*1024 + lt + j;
                if (t < TOUT && acc[s][g][j] > bv) { bv = acc[s][g][j]; bi = (aA+s)*TOUT + t; }
            }
            wave_amax(bv, bi);
            if (lane == 0) { wv[s*8 + g*4 + w] = bv; wi[s*8 + g*4 + w] = bi; }
        }
    }
    __syncthreads();
    if (tid < 8) {     // (s, chunk-in-tile c): partials at s*8 + (c>>1)*4 + (c&1)*2
        int s = tid >> 2, c = tid & 3;
        int base = s*8 + (c >> 1)*4 + (c & 1)*2;
        float v0 = wv[base];   int i0 = wi[base];
        float v1 = wv[base+1]; int i1 = wi[base+1];
        if (v1 > v0 || (v1 == v0 && i1 < i0)) { v0 = v1; i0 = i1; }
        int chunk = blockIdx.x*4 + c;
        if (chunk < NCHUNK) {
            segval[((size_t)b*A + aA + s)*NCP + chunk] = v0;
            segidx[((size_t)b*A + aA + s)*NCP + chunk] = i0;
        }
    }
}

// ---------------- one matching-pursuit iteration (shared coop/fallback) ----------------
__device__ __forceinline__ void dev_iter2(int a0, int b, int tid, int last,
        const float* __restrict__ avc, const int* __restrict__ aic,
        float* __restrict__ avn, int* __restrict__ ain,
        const float* __restrict__ rin, float* __restrict__ rout,
        float* __restrict__ recon, const float* __restrict__ dn,
        float* __restrict__ segval, int* __restrict__ segidx, SmemIt& sm) {
    const int aA = a0*2;
    const int lane = tid & 63, w = tid >> 6;
    // pick (redundant, deterministic across blocks of same b)
    {
        float bv = avc[b*A + tid]; int bi = aic[b*A + tid];
        wave_amax(bv, bi);
        if (lane == 0) { sm.wv[w] = bv; sm.wi[w] = bi; }
        __syncthreads();
        if (tid == 0) {
            bv = sm.wv[0]; bi = sm.wi[0];
            for (int j = 1; j < 4; j++)
                if (sm.wv[j] > bv || (sm.wv[j] == bv && sm.wi[j] < bi)) { bv = sm.wv[j]; bi = sm.wi[j]; }
            sm.fv = bv; sm.fi = bi;
        }
        __syncthreads();
    }
    float val = sm.fv; int idx = sm.fi;
    int atom = idx / TOUT, pos = idx - atom*TOUT;
    sm.sel[tid] = dn[atom*K + tid];
    sm.dn[tid] = dn[aA*K + tid];
    sm.dn[256 + tid] = dn[aA*K + 256 + tid];

    int lo = pos - (K-1); if (lo < 0) lo = 0;
    int c_lo = lo >> 9;
    int tbase = c_lo * CHUNK;

    if (!last) {   // stage 2 chunks + K halo (324 quads)
        const float4* rin4 = (const float4*)(rin + (size_t)b*TP);
        float4* s4 = (float4*)sm.rp;
        for (int i = tid; i < 324; i += 256) {
            int g = tbase/4 + i;
            float4 v = {0.f,0.f,0.f,0.f};
            if (g*4 < TP) v = rin4[g];
            s4[i] = v;
        }
    }
    __syncthreads();
    if (!last) {   // distributed rp copy+update (blocks a0=0..16, 1 quad/thread)
        const float4* rin4 = (const float4*)(rin + (size_t)b*TP);
        float4* rout4 = (float4*)(rout + (size_t)b*TP);
        int i = a0*256 + tid;
        if (i < TP/4) {
            float4 v = rin4[i];
            int o = i*4 - pos;
            if (o > -4 && o < K) {
                if (o+0 >= 0 && o+0 < K) v.x -= val * sm.sel[o+0];
                if (o+1 >= 0 && o+1 < K) v.y -= val * sm.sel[o+1];
                if (o+2 >= 0 && o+2 < K) v.z -= val * sm.sel[o+2];
                if (o+3 >= 0 && o+3 < K) v.w -= val * sm.sel[o+3];
            }
            rout4[i] = v;
        }
    }
    if (a0 == 0) recon[(size_t)b*TP + pos + tid] += val * sm.sel[tid];
    if (last) return;

    sm.rp[pos - tbase + tid] -= val * sm.sel[tid];
    __syncthreads();

    // recompute 1024 outputs [tbase, tbase+1024) for both atoms
    const float4* srp4 = (const float4*)sm.rp;
    const float4* dA4 = (const float4*)sm.dn;
    const float4* dB4 = dA4 + 64;
    float cA[4] = {0,0,0,0}, cB[4] = {0,0,0,0};
    float4 p = srp4[tid];
    #pragma unroll 4
    for (int kq = 0; kq < 64; kq++) {
        float4 pn = srp4[tid + kq + 1];
        float4 dA = dA4[kq], dB = dB4[kq];
        TAP(cA[0], p.x,p.y,p.z,p.w, dA); TAP(cA[1], p.y,p.z,p.w,pn.x, dA);
        TAP(cA[2], p.z,p.w,pn.x,pn.y, dA); TAP(cA[3], p.w,pn.x,pn.y,pn.z, dA);
        TAP(cB[0], p.x,p.y,p.z,p.w, dB); TAP(cB[1], p.y,p.z,p.w,pn.x, dB);
        TAP(cB[2], p.z,p.w,pn.x,pn.y, dB); TAP(cB[3], p.w,pn.x,pn.y,pn.z, dB);
        p = pn;
    }
    const int lt = tid * 4;
    float bvA = -INFINITY, bvB = -INFINITY;
    int biA = 0x7fffffff, biB = 0x7fffffff;
    #pragma unroll
    for (int j = 0; j < 4; j++) {
        int t = tbase + lt + j;
        if (t < TOUT) {
            if (cA[j] > bvA) { bvA = cA[j]; biA = aA*TOUT + t; }
            if (cB[j] > bvB) { bvB = cB[j]; biB = (aA+1)*TOUT + t; }
        }
    }
    wave_amax(bvA, biA); wave_amax(bvB, biB);
    if (lane == 0) { sm.wv[w] = bvA; sm.wi[w] = biA; sm.wv[8+w] = bvB; sm.wi[8+w] = biB; }
    __syncthreads();
    if (tid < 4) {     // (s = tid>>1, c = tid&1): partials s*8 + c*2 + {0,1}
        int s = tid >> 1, c = tid & 1;
        int base = s*8 + c*2;
        float v0 = sm.wv[base];   int i0 = sm.wi[base];
        float v1 = sm.wv[base+1]; int i1 = sm.wi[base+1];
        if (v1 > v0 || (v1 == v0 && i1 < i0)) { v0 = v1; i0 = i1; }
        int chunk = c_lo + c;
        if (chunk < NCHUNK) {
            segval[((size_t)b*A + aA + s)*NCP + chunk] = v0;
            segidx[((size_t)b*A + aA + s)*NCP + chunk] = i0;
        }
    }
    __syncthreads();
    if (w < 2) {   // refresh per-atom best over all chunks
        int at = aA + w;
        float bv = -INFINITY; int bi = 0x7fffffff;
        if (lane < NCHUNK) {
            bv = segval[((size_t)b*A + at)*NCP + lane];
            bi = segidx[((size_t)b*A + at)*NCP + lane];
        }
        wave_amax(bv, bi);
        if (lane == 0) { avn[b*A + at] = bv; ain[b*A + at] = bi; }
    }
}

// ---------------- cooperative iteration kernel (512 blocks x 256 thr, R8-proven) ----------------
__global__ void __launch_bounds__(256, 2)
k_it(const float* __restrict__ dn, float* __restrict__ rp0, float* __restrict__ rp1,
     float* __restrict__ recon, float* __restrict__ segval, int* __restrict__ segidx,
     float* __restrict__ abv0, int* __restrict__ abi0,
     float* __restrict__ abv1, int* __restrict__ abi1,
     float* __restrict__ out, unsigned* __restrict__ bar) {
    __shared__ SmemIt sm;
    const int bid = blockIdx.x, tid = threadIdx.x;
    const int a0 = bid & (NBB-1), b = bid >> 7;
    const int lane = tid & 63, w = tid >> 6;
    unsigned* bar_b = bar + b*256;
    unsigned gen = 0;
    // phase 0: per-atom best from conv's segval (own atoms only)
    if (w < 2) {
        int atom = a0*2 + w;
        float bv = -INFINITY; int bi = 0x7fffffff;
        if (lane < NCHUNK) {
            bv = segval[((size_t)b*A + atom)*NCP + lane];
            bi = segidx[((size_t)b*A + atom)*NCP + lane];
        }
        wave_amax(bv, bi);
        if (lane == 0) { abv0[b*A + atom] = bv; abi0[b*A + atom] = bi; }
    }
    gen++; gbar(bar_b, gen*NBB);
    const float* rin = rp0; float* rout = rp1;
    const float* avc = abv0; const int* aic = abi0;
    float* avn = abv1; int* ain = abi1;
    for (int it = 0; it < ITERS; it++) {
        dev_iter2(a0, b, tid, it == ITERS-1, avc, aic, avn, ain,
                  rin, rout, recon, dn, segval, segidx, sm);
        { const float* t1 = rin; rin = rout; rout = (float*)t1; }
        { const float* t2 = avc; avc = avn; avn = (float*)t2; }
        { const int*   t3 = aic; aic = ain; ain = (int*)t3; }
        gen++; gbar(bar_b, gen*NBB);
    }
    for (int i = a0*256 + tid; i < T; i += NBB*256)
        out[b*T + i] = recon[(size_t)b*TP + PAD + i];
}

// ---------------- non-cooperative fallback ----------------
__global__ void k_f_abest(const float* __restrict__ segval, const int* __restrict__ segidx,
                          float* __restrict__ abv, int* __restrict__ abi) {
    int b = blockIdx.x, a = threadIdx.x;
    float bv = -INFINITY; int bi = 0x7fffffff;
    for (int c = 0; c < NCHUNK; c++) {
        float v = segval[((size_t)b*A + a)*NCP + c];
        int  ix = segidx[((size_t)b*A + a)*NCP + c];
        if (v > bv || (v == bv && ix < bi)) { bv = v; bi = ix; }
    }
    abv[b*A + a] = bv; abi[b*A + a] = bi;
}
__global__ void __launch_bounds__(256, 2) k_f_iter(int last,
        const float* avc, const int* aic, float* avn, int* ain,
        const float* rin, float* rout, float* recon, const float* dn,
        float* segval, int* segidx) {
    __shared__ SmemIt sm;
    dev_iter2(blockIdx.x & (NBB-1), blockIdx.x >> 7, threadIdx.x, last,
              avc, aic, avn, ain, rin, rout, recon, dn, segval, segidx, sm);
}
__global__ void k_f_out(const float* __restrict__ recon, float* __restrict__ out) {
    int i = blockIdx.x * blockDim.x + threadIdx.x;
    if (i >= B*T) return;
    int b = i / T, t = i - b*T;
    out[i] = recon[(size_t)b*TP + PAD + t];
}

extern "C" void kernel_launch(void* const* d_in, const int* in_sizes, int n_in,
                              void* d_out, int out_size, void* d_ws, size_t ws_size,
                              hipStream_t stream) {
    const float* x = (const float*)d_in[0];
    const float* d = (const float*)d_in[1];
    float* out = (float*)d_out;

    float* ws     = (float*)d_ws;
    float* dn     = ws;                                   // A*K
    float* rp0    = dn  + (size_t)A*K;                    // B*TP
    float* rp1    = rp0 + (size_t)B*TP;                   // B*TP
    float* recon  = rp1 + (size_t)B*TP;                   // B*TP
    float* segval = recon + (size_t)B*TP;                 // B*A*NCP
    int*   segidx = (int*)(segval + (size_t)B*A*NCP);     // B*A*NCP
    float* abv0   = (float*)(segidx + (size_t)B*A*NCP);   // B*A
    float* abv1   = abv0 + (size_t)B*A;                   // B*A
    int*   abi0   = (int*)(abv1 + (size_t)B*A);           // B*A
    int*   abi1   = abi0 + (size_t)B*A;                   // B*A
    unsigned* bar = (unsigned*)(abi1 + (size_t)B*A);      // 4 per-batch counters, 1 KB apart

    // phase 1+2: ordinary launches — big grids, no co-residency constraint
    k_norm_init<<<A, 256, 0, stream>>>(x, d, dn, rp0, recon);
    k_conv<<<dim3(NTILE, A/2, B), 256, 0, stream>>>(rp0, dn, segval, segidx);

    // phase 3: cooperative iterations (R8-proven 512x256 shape)
    int nb = 0, ncu = 0;
    hipError_t e1 = hipOccupancyMaxActiveBlocksPerMultiprocessor(&nb, (const void*)k_it, 256, 0);
    hipError_t e2 = hipDeviceGetAttribute(&ncu, hipDeviceAttributeMultiprocessorCount, 0);
    if (e1 == hipSuccess && e2 == hipSuccess && (long)nb * ncu >= NITB) {
        hipMemsetAsync(bar, 0, 4*256*sizeof(unsigned), stream);
        void* args[] = {(void*)&dn, (void*)&rp0, (void*)&rp1, (void*)&recon,
                        (void*)&segval, (void*)&segidx,
                        (void*)&abv0, (void*)&abi0, (void*)&abv1, (void*)&abi1,
                        (void*)&out, (void*)&bar};
        if (hipLaunchCooperativeKernel((const void*)k_it, dim3(NITB), dim3(256),
                                       args, 0, stream) == hipSuccess)
            return;
    }
    // fallback: non-cooperative, double-buffered, race-free
    k_f_abest<<<B, 256, 0, stream>>>(segval, segidx, abv0, abi0);
    float* rbuf[2] = {rp0, rp1};
    float* av[2]   = {abv0, abv1};
    int*   ai[2]   = {abi0, abi1};
    for (int it = 0; it < ITERS; it++) {
        k_f_iter<<<NITB, 256, 0, stream>>>(it == ITERS-1 ? 1 : 0,
                                           av[it & 1], ai[it & 1],
                                           av[(it + 1) & 1], ai[(it + 1) & 1],
                                           rbuf[it & 1], rbuf[(it + 1) & 1],
                                           recon, dn, segval, segidx);
    }
    k_f_out<<<(B*T + 255)/256, 256, 0, stream>>>(recon, out);
}